// Round 10
// baseline (263.790 us; speedup 1.0000x reference)
//
#include <hip/hip_runtime.h>
#include <math.h>

// Problem constants
#define BATCH 2
#define NTOK  2048
#define DIMC  1024
#define NH    16
#define HD    64
// exp base-2 folding: softmax exp(s*0.125) == exp2(s * 0.125*log2(e))
#define SOFT_K2 0.18033688011112042f

typedef __bf16 bf16;
typedef __attribute__((ext_vector_type(8))) __bf16 bf16x8;
typedef __attribute__((ext_vector_type(4))) __bf16 bf16x4;
typedef __attribute__((ext_vector_type(4))) float f32x4;

// async global->LDS, 16B per lane; LDS dest is wave-uniform base + lane*16
__device__ __forceinline__ void load_lds16(const void* g, void* l) {
    __builtin_amdgcn_global_load_lds(
        (const __attribute__((address_space(1))) void*)g,
        (__attribute__((address_space(3))) void*)l, 16, 0, 0);
}
__device__ __forceinline__ f32x4 mfma16(bf16x8 a, bf16x8 b, f32x4 c) {
    return __builtin_amdgcn_mfma_f32_16x16x32_bf16(a, b, c, 0, 0, 0);
}

// ---------------------------------------------------------------------------
// Fused fp32->bf16 cast of x, W_qkv, W_proj. 1024 elems per block.
// ---------------------------------------------------------------------------
__global__ __launch_bounds__(256) void cast3(
    const float* __restrict__ x,  const float* __restrict__ w1, const float* __restrict__ w2,
    bf16* __restrict__ xb, bf16* __restrict__ w1b, bf16* __restrict__ w2b)
{
    int blk = blockIdx.x;
    const float* src; bf16* dst; size_t base;
    if (blk < 4096)      { src = x;  dst = xb;  base = (size_t)blk * 1024; }
    else if (blk < 7168) { src = w1; dst = w1b; base = (size_t)(blk - 4096) * 1024; }
    else                 { src = w2; dst = w2b; base = (size_t)(blk - 7168) * 1024; }
    size_t i = base + (size_t)threadIdx.x * 4;
    float4 v = *(const float4*)(src + i);
    bf16x4 r;
    r[0] = (bf16)v.x; r[1] = (bf16)v.y; r[2] = (bf16)v.z; r[3] = (bf16)v.w;
    *(bf16x4*)(dst + i) = r;
}

// ---------------------------------------------------------------------------
// Direct-from-global MFMA GEMM core (round 9): NO LDS staging, NO barriers,
// ONE wave per block computing a 64x64 tile.
// Rationale: round-8 counters showed the LDS-staged GEMM at the LDS-BW
// ceiling (48 KB/block-iter ~= 85 B/cyc/CU = m134 ceiling; MfmaUtil 13%,
// VALUBusy 8%). Direct loads: fragment pattern = 16 rows x 64 B contiguous
// per row (4 quads cover one 64B line) -> zero overfetch; K=1024 -> all
// k-offsets fit imm13 (kt*2 <= 1984) -> zero per-iter address VALU; no
// barrier -> compiler pipelines plain loads with vmcnt(N), and independent
// waves (12/CU for qkv) hide the rest.
// __launch_bounds__(64,3): pin ~170 VGPR so acc[16xf32x4]+frags stay
// resident (default for 64-thread blocks may target 64 VGPR -> spill).
// ---------------------------------------------------------------------------
__device__ __forceinline__ void gemm_tile_64x64(
    const bf16* __restrict__ A, const bf16* __restrict__ B,
    int m0, int n0, int K, int lm, int quad, f32x4 acc[4][4])
{
    const bf16* Ab[4]; const bf16* Bb[4];
#pragma unroll
    for (int i = 0; i < 4; ++i) {
        Ab[i] = A + (size_t)(m0 + i * 16 + lm) * K + quad * 8;
        Bb[i] = B + (size_t)(n0 + i * 16 + lm) * K + quad * 8;
    }
#pragma unroll
    for (int kk = 0; kk < 1024; kk += 32) {   // K == 1024 for all our GEMMs
        bf16x8 af[4], bf_[4];
#pragma unroll
        for (int i = 0; i < 4; ++i) af[i]  = *(const bf16x8*)(Ab[i] + kk);
#pragma unroll
        for (int i = 0; i < 4; ++i) bf_[i] = *(const bf16x8*)(Bb[i] + kk);
#pragma unroll
        for (int mi = 0; mi < 4; ++mi)
#pragma unroll
            for (int ni = 0; ni < 4; ++ni)
                acc[mi][ni] = mfma16(af[mi], bf_[ni], acc[mi][ni]);
    }
}

// QKV GEMM: C[m,n] = sum_k A[m,k]*W[n,k]. n<2048 (Q,K) -> row-major qkvb
// (stride 3072); n>=2048 (V) -> transposed Vt[b][h][d][tok] via wave-private
// LDS (single wave: DS ops in-order, no barrier needed).
__global__ __launch_bounds__(64, 3) void gemm_qkv(
    const bf16* __restrict__ A, const bf16* __restrict__ B,
    bf16* __restrict__ Cq, bf16* __restrict__ vt,
    int M, int N, int K)
{
    __shared__ __align__(16) bf16 T[64 * 72];   // epilogue transpose only

    const int lane = threadIdx.x;
    const int lm = lane & 15, quad = lane >> 4;
    const int m0 = blockIdx.y * 64, n0 = blockIdx.x * 64;

    f32x4 acc[4][4];
    f32x4 z4 = {0.f, 0.f, 0.f, 0.f};
#pragma unroll
    for (int i = 0; i < 4; ++i)
#pragma unroll
        for (int j = 0; j < 4; ++j) acc[i][j] = z4;

    gemm_tile_64x64(A, B, m0, n0, K, lm, quad, acc);

    // D layout: col=lane&15, row=quad*4+reg  [m89-verified]
    if (n0 >= 2048) {
        // V: wave-private LDS transpose -> coalesced bf16x8 stores
#pragma unroll
        for (int ni = 0; ni < 4; ++ni) {
            const int dl = ni * 16 + lm;          // local col (=Vt row d)
#pragma unroll
            for (int mi = 0; mi < 4; ++mi)
#pragma unroll
                for (int r = 0; r < 4; ++r)
                    T[dl * 72 + mi * 16 + quad * 4 + r] = (bf16)acc[mi][ni][r];
        }
        // single wave: ds_write->ds_read ordered by lgkmcnt, no barrier
        const int gcol0 = n0 - 2048;
        const int bb = m0 >> 11, tokbase = m0 & 2047;
#pragma unroll
        for (int rep = 0; rep < 8; ++rep) {
            const int g = rep * 64 + lane;
            const int d = g >> 3, tc = g & 7;     // 8 lanes x 16B = 128B per d-row
            bf16x8 v = *(const bf16x8*)&T[d * 72 + tc * 8];
            const int gcol = gcol0 + d, hh = gcol >> 6, dd = gcol & 63;
            *(bf16x8*)(vt + ((size_t)((bb * NH + hh) * HD + dd)) * NTOK + tokbase + tc * 8) = v;
        }
    } else {
#pragma unroll
        for (int ni = 0; ni < 4; ++ni) {
            const int col = n0 + ni * 16 + lm;
#pragma unroll
            for (int mi = 0; mi < 4; ++mi)
#pragma unroll
                for (int r = 0; r < 4; ++r) {
                    const int row = m0 + mi * 16 + quad * 4 + r;
                    Cq[(size_t)row * N + col] = (bf16)acc[mi][ni][r];
                }
        }
    }
}

// Proj GEMM: C[m,n] = sum_k A[m,k]*B[n,k] + bias[n], fp32 out.
__global__ __launch_bounds__(64, 3) void gemm_proj(
    const bf16* __restrict__ A, const bf16* __restrict__ B,
    const float* __restrict__ bias, float* __restrict__ C,
    int M, int N, int K)
{
    const int lane = threadIdx.x;
    const int lm = lane & 15, quad = lane >> 4;
    const int m0 = blockIdx.y * 64, n0 = blockIdx.x * 64;

    f32x4 acc[4][4];
    f32x4 z4 = {0.f, 0.f, 0.f, 0.f};
#pragma unroll
    for (int i = 0; i < 4; ++i)
#pragma unroll
        for (int j = 0; j < 4; ++j) acc[i][j] = z4;

    gemm_tile_64x64(A, B, m0, n0, K, lm, quad, acc);

#pragma unroll
    for (int ni = 0; ni < 4; ++ni) {
        const int col = n0 + ni * 16 + lm;
        const float bi = bias[col];
#pragma unroll
        for (int mi = 0; mi < 4; ++mi)
#pragma unroll
            for (int r = 0; r < 4; ++r) {
                const int row = m0 + mi * 16 + quad * 4 + r;
                C[(size_t)row * N + col] = acc[mi][ni][r] + bi;
            }
    }
}

// ---------------------------------------------------------------------------
// Flash attention, bf16 MFMA, software-pipelined K-loop (round 6, unchanged).
// ---------------------------------------------------------------------------
__global__ __launch_bounds__(256, 2) void attn_mfma(
    const bf16* __restrict__ qkv,   // [B,N,3C] bf16 (Q,K cols only)
    const bf16* __restrict__ Vt,    // [B,H,D,N] bf16
    bf16* __restrict__ att)         // [B,N,C]  bf16
{
    __shared__ __align__(16) bf16 Ks[2][64 * 64];     // chunk = dc*64 + krow
    __shared__ __align__(16) bf16 Vs[2][64 * 64];     // chunk = kc*64 + d
    __shared__ __align__(16) bf16 Ps[2][128 * 72];    // [q][key] pitch 72

    const int n0 = blockIdx.x * 128, h = blockIdx.y, b = blockIdx.z;
    const int tid = threadIdx.x, w = tid >> 6, lane = tid & 63;
    const int lm = lane & 15, quad = lane >> 4;

    const size_t rs = (size_t)(3 * DIMC);
    const bf16* qbase  = qkv + (size_t)b * NTOK * rs + h * HD;
    const bf16* kbase  = qbase + DIMC;
    const bf16* vtbase = Vt + ((size_t)(b * NH + h) * HD) * NTOK;

    // Q A-frags in registers
    bf16x8 aq[2][2];
#pragma unroll
    for (int g = 0; g < 2; ++g)
#pragma unroll
        for (int s2 = 0; s2 < 2; ++s2)
            aq[g][s2] = *(const bf16x8*)(qbase
                + (size_t)(n0 + w * 32 + g * 16 + lm) * rs + s2 * 32 + quad * 8);

    const int l0 = (w * 2 + 0) * 64 + lane, l1 = (w * 2 + 1) * 64 + lane;
    const bf16* kg0 = kbase + (size_t)(l0 & 63) * rs + (l0 >> 6) * 8;
    const bf16* kg1 = kbase + (size_t)(l1 & 63) * rs + (l1 >> 6) * 8;
    const bf16* vg0 = vtbase + (size_t)(l0 & 63) * NTOK + (l0 >> 6) * 8;
    const bf16* vg1 = vtbase + (size_t)(l1 & 63) * NTOK + (l1 >> 6) * 8;

#define STAGE_K(tile, dst) do { \
    load_lds16(kg0 + (size_t)(tile) * 64 * rs, (dst) + (w * 2 + 0) * 512); \
    load_lds16(kg1 + (size_t)(tile) * 64 * rs, (dst) + (w * 2 + 1) * 512); } while (0)
#define STAGE_V(tile, dst) do { \
    load_lds16(vg0 + (size_t)(tile) * 64, (dst) + (w * 2 + 0) * 512); \
    load_lds16(vg1 + (size_t)(tile) * 64, (dst) + (w * 2 + 1) * 512); } while (0)

    f32x4 O[2][4];
    f32x4 z4 = {0.f, 0.f, 0.f, 0.f};
#pragma unroll
    for (int g = 0; g < 2; ++g)
#pragma unroll
        for (int ni = 0; ni < 4; ++ni) O[g][ni] = z4;
    float lsum[2][4] = {{0.f, 0.f, 0.f, 0.f}, {0.f, 0.f, 0.f, 0.f}};

#define COMPUTE_S_PS(Ksb, Psb) do {                                           \
    f32x4 S[2][4];                                                            \
    for (int g = 0; g < 2; ++g)                                               \
        for (int ni = 0; ni < 4; ++ni) S[g][ni] = z4;                         \
    for (int s2 = 0; s2 < 2; ++s2)                                            \
        for (int ni = 0; ni < 4; ++ni) {                                      \
            bf16x8 bk = *(const bf16x8*)((Ksb)                                \
                + ((s2 * 4 + quad) * 64 + ni * 16 + lm) * 8);                 \
            S[0][ni] = mfma16(aq[0][s2], bk, S[0][ni]);                       \
            S[1][ni] = mfma16(aq[1][s2], bk, S[1][ni]);                       \
        }                                                                     \
    for (int g = 0; g < 2; ++g)                                               \
        for (int ni = 0; ni < 4; ++ni)                                        \
            for (int r = 0; r < 4; ++r) {                                     \
                const float p = __builtin_amdgcn_exp2f(S[g][ni][r] * SOFT_K2);\
                (Psb)[(w * 32 + g * 16 + quad * 4 + r) * 72 + ni * 16 + lm]   \
                    = (bf16)p;                                                \
                lsum[g][r] += p;                                              \
            }                                                                 \
} while (0)

#define COMPUTE_PV(Psb, Vsb) do {                                             \
    for (int s2 = 0; s2 < 2; ++s2) {                                          \
        bf16x8 ap0 = *(const bf16x8*)((Psb)                                   \
            + (w * 32 + lm) * 72 + s2 * 32 + quad * 8);                       \
        bf16x8 ap1 = *(const bf16x8*)((Psb)                                   \
            + (w * 32 + 16 + lm) * 72 + s2 * 32 + quad * 8);                  \
        for (int ni = 0; ni < 4; ++ni) {                                      \
            bf16x8 bv = *(const bf16x8*)((Vsb)                                \
                + ((s2 * 4 + quad) * 64 + ni * 16 + lm) * 8);                 \
            O[0][ni] = mfma16(ap0, bv, O[0][ni]);                             \
            O[1][ni] = mfma16(ap1, bv, O[1][ni]);                             \
        }                                                                     \
    }                                                                         \
} while (0)

    const int NT = NTOK / 64;   // 32

    STAGE_K(0, Ks[0]);
    STAGE_V(0, Vs[0]);
    STAGE_K(1, Ks[1]);
    __syncthreads();
    COMPUTE_S_PS(Ks[0], Ps[0]);

    for (int t = 0; t < NT; ++t) {
        __syncthreads();
        if (t + 2 < NT) STAGE_K(t + 2, Ks[t & 1]);
        if (t + 1 < NT) STAGE_V(t + 1, Vs[(t + 1) & 1]);
        if (t + 1 < NT) COMPUTE_S_PS(Ks[(t + 1) & 1], Ps[(t + 1) & 1]);
        COMPUTE_PV(Ps[t & 1], Vs[t & 1]);
    }

#undef STAGE_K
#undef STAGE_V
#undef COMPUTE_S_PS
#undef COMPUTE_PV

#pragma unroll
    for (int g = 0; g < 2; ++g)
#pragma unroll
        for (int r = 0; r < 4; ++r) {
#pragma unroll
            for (int msk = 1; msk < 16; msk <<= 1)
                lsum[g][r] += __shfl_xor(lsum[g][r], msk);
        }

#pragma unroll
    for (int g = 0; g < 2; ++g)
#pragma unroll
        for (int r = 0; r < 4; ++r) {
            const float invl = 1.0f / lsum[g][r];
            const size_t row = (size_t)(b * NTOK + n0 + w * 32 + g * 16 + quad * 4 + r);
#pragma unroll
            for (int ni = 0; ni < 4; ++ni)
                att[row * DIMC + h * HD + ni * 16 + lm] = (bf16)(O[g][ni][r] * invl);
        }
}

// ---------------------------------------------------------------------------
extern "C" void kernel_launch(void* const* d_in, const int* in_sizes, int n_in,
                              void* d_out, int out_size, void* d_ws, size_t ws_size,
                              hipStream_t stream)
{
    const float* x      = (const float*)d_in[0];   // [2,2048,1024]
    const float* W_qkv  = (const float*)d_in[1];   // [3072,1024]
    const float* W_proj = (const float*)d_in[2];   // [1024,1024]
    const float* b_proj = (const float*)d_in[3];   // [1024]
    float* out = (float*)d_out;

    char* ws = (char*)d_ws;
    bf16* xb   = (bf16*)ws;                        //  8 MiB
    bf16* w1b  = (bf16*)(ws + (8u  << 20));        //  6 MiB
    bf16* w2b  = (bf16*)(ws + (14u << 20));        //  2 MiB
    bf16* qkvb = (bf16*)(ws + (16u << 20));        // 24 MiB (V cols unused)
    bf16* vt   = (bf16*)(ws + (40u << 20));        //  8 MiB
    bf16* attb = (bf16*)(ws + (48u << 20));        //  8 MiB (total 56 MiB)

    const int M = BATCH * NTOK;   // 4096

    cast3<<<8192, 256, 0, stream>>>(x, W_qkv, W_proj, xb, w1b, w2b);

    // 3072 one-wave blocks (12 waves/CU), no LDS/barriers in the K-loop
    gemm_qkv<<<dim3((3 * DIMC) / 64, M / 64), 64, 0, stream>>>(
        xb, w1b, qkvb, vt, M, 3 * DIMC, DIMC);

    attn_mfma<<<dim3(NTOK / 128, NH, BATCH), 256, 0, stream>>>(qkvb, vt, attb);

    // 1024 one-wave blocks (4/CU)
    gemm_proj<<<dim3(DIMC / 64, M / 64), 64, 0, stream>>>(
        attb, w2b, b_proj, out, M, DIMC, DIMC);
}

// Round 11
// 221.174 us; speedup vs baseline: 1.1927x; 1.1927x over previous
//
#include <hip/hip_runtime.h>
#include <math.h>

// Problem constants
#define BATCH 2
#define NTOK  2048
#define DIMC  1024
#define NH    16
#define HD    64
// exp base-2 folding: softmax exp(s*0.125) == exp2(s * 0.125*log2(e))
#define SOFT_K2 0.18033688011112042f

typedef __bf16 bf16;
typedef __attribute__((ext_vector_type(8))) __bf16 bf16x8;
typedef __attribute__((ext_vector_type(4))) __bf16 bf16x4;
typedef __attribute__((ext_vector_type(4))) float f32x4;

// async global->LDS, 16B per lane; LDS dest is wave-uniform base + lane*16
__device__ __forceinline__ void load_lds16(const void* g, void* l) {
    __builtin_amdgcn_global_load_lds(
        (const __attribute__((address_space(1))) void*)g,
        (__attribute__((address_space(3))) void*)l, 16, 0, 0);
}
__device__ __forceinline__ f32x4 mfma16(bf16x8 a, bf16x8 b, f32x4 c) {
    return __builtin_amdgcn_mfma_f32_16x16x32_bf16(a, b, c, 0, 0, 0);
}

// ---------------------------------------------------------------------------
// Fused fp32->bf16 cast of x, W_qkv, W_proj. 1024 elems per block.
// ---------------------------------------------------------------------------
__global__ __launch_bounds__(256) void cast3(
    const float* __restrict__ x,  const float* __restrict__ w1, const float* __restrict__ w2,
    bf16* __restrict__ xb, bf16* __restrict__ w1b, bf16* __restrict__ w2b)
{
    int blk = blockIdx.x;
    const float* src; bf16* dst; size_t base;
    if (blk < 4096)      { src = x;  dst = xb;  base = (size_t)blk * 1024; }
    else if (blk < 7168) { src = w1; dst = w1b; base = (size_t)(blk - 4096) * 1024; }
    else                 { src = w2; dst = w2b; base = (size_t)(blk - 7168) * 1024; }
    size_t i = base + (size_t)threadIdx.x * 4;
    float4 v = *(const float4*)(src + i);
    bf16x4 r;
    r[0] = (bf16)v.x; r[1] = (bf16)v.y; r[2] = (bf16)v.z; r[3] = (bf16)v.w;
    *(bf16x4*)(dst + i) = r;
}

// ---------------------------------------------------------------------------
// Round 10 GEMMs: register-prefetch double-buffer, BK=64.
// Why: __syncthreads() forces s_waitcnt vmcnt(0), draining global_load_lds
// prefetch at every barrier (round 8/9 post-mortems: ~1850 cyc/block-iter
// ~= one memory round trip; LDS was at only ~26 B/cyc, NOT the ceiling).
// Plain loads into VGPRs are not LDS-observable -> barriers drain only
// lgkmcnt; the t+1 loads fly under tile-t compute. BK=64 halves barrier
// count. Single 32 KB LDS buffer; chunk layout [kc][row] of 16B chunks.
// ---------------------------------------------------------------------------

// QKV GEMM: 128x128 tile. n<2048 (Q,K) -> row-major qkvb (stride 3072);
// n>=2048 (V) -> transposed Vt[b][h][d][tok] via LDS round-trip.
__global__ __launch_bounds__(256, 3) void gemm_qkv(
    const bf16* __restrict__ A, const bf16* __restrict__ B,
    bf16* __restrict__ Cq, bf16* __restrict__ vt,
    int M, int N, int K)
{
    // staging: As elems [0,8192), Bs [8192,16384); epilogue T uses 128*136
    __shared__ __align__(16) bf16 smem[17408];

    const int tid  = threadIdx.x;
    const int w    = tid >> 6, lane = tid & 63;
    const int wm   = w & 1,  wn = w >> 1;
    const int m0   = blockIdx.y * 128, n0 = blockIdx.x * 128;
    const int lm   = lane & 15, quad = lane >> 4;

    // staging addresses: thread covers chunks c = t*256+tid = kc*128+row,
    // row = tid&127 (same row all t), kc = t*2 + (tid>>7)
    const bf16* Arow = A + (size_t)(m0 + (tid & 127)) * K + (tid >> 7) * 8;
    const bf16* Brow = B + (size_t)(n0 + (tid & 127)) * K + (tid >> 7) * 8;

    bf16x8 ar[4], br[4];
#define QKV_LOADREG(kt) do {                                    \
    for (int t = 0; t < 4; ++t) {                               \
        ar[t] = *(const bf16x8*)(Arow + (kt) + t * 16);         \
        br[t] = *(const bf16x8*)(Brow + (kt) + t * 16);         \
    } } while (0)
#define QKV_DSWRITE() do {                                      \
    for (int t = 0; t < 4; ++t) {                               \
        *(bf16x8*)(smem + (t * 256 + tid) * 8) = ar[t];         \
        *(bf16x8*)(smem + 8192 + (t * 256 + tid) * 8) = br[t];  \
    } } while (0)

    f32x4 acc[4][4];
    f32x4 z4 = {0.f, 0.f, 0.f, 0.f};
#pragma unroll
    for (int i = 0; i < 4; ++i)
#pragma unroll
        for (int j = 0; j < 4; ++j) acc[i][j] = z4;

    const int NI = K / 64;            // 16
    QKV_LOADREG(0);
    QKV_DSWRITE();                    // compiler waits vmcnt before ds_write
    __syncthreads();                  // lgkm drain only
    for (int it = 0; it < NI; ++it) {
        if (it + 1 < NI) QKV_LOADREG((it + 1) * 64);   // fly under compute
#pragma unroll
        for (int s = 0; s < 2; ++s) { // two K=32 halves of the BK=64 tile
            bf16x8 af[4], bf_[4];
#pragma unroll
            for (int mi = 0; mi < 4; ++mi)
                af[mi] = *(const bf16x8*)(smem
                    + ((s * 4 + quad) * 128 + wm * 64 + mi * 16 + lm) * 8);
#pragma unroll
            for (int ni = 0; ni < 4; ++ni)
                bf_[ni] = *(const bf16x8*)(smem + 8192
                    + ((s * 4 + quad) * 128 + wn * 64 + ni * 16 + lm) * 8);
#pragma unroll
            for (int mi = 0; mi < 4; ++mi)
#pragma unroll
                for (int ni = 0; ni < 4; ++ni)
                    acc[mi][ni] = mfma16(af[mi], bf_[ni], acc[mi][ni]);
        }
        __syncthreads();              // all reads of buffer done
        if (it + 1 < NI) QKV_DSWRITE();
        __syncthreads();              // writes visible (lgkm only)
    }
#undef QKV_LOADREG
#undef QKV_DSWRITE

    // D layout: col=lane&15, row=quad*4+reg  [m89-verified]
    if (n0 >= 2048) {
        // V: transpose via LDS, then coalesced bf16x8 stores to Vt
        bf16* T = smem;               // [128 d][136 pitch]
#pragma unroll
        for (int ni = 0; ni < 4; ++ni) {
            const int dl = wn * 64 + ni * 16 + lm;
#pragma unroll
            for (int mi = 0; mi < 4; ++mi)
#pragma unroll
                for (int r = 0; r < 4; ++r)
                    T[dl * 136 + wm * 64 + mi * 16 + quad * 4 + r] = (bf16)acc[mi][ni][r];
        }
        __syncthreads();
        const int gcol0 = n0 - 2048;
        const int bb = m0 >> 11, tokbase = m0 & 2047;
#pragma unroll
        for (int rep = 0; rep < 8; ++rep) {
            const int g = rep * 256 + tid;
            const int d = g >> 4, tc = g & 15;   // 16 lanes per d-row -> 256B runs
            bf16x8 v = *(const bf16x8*)&T[d * 136 + tc * 8];
            const int gcol = gcol0 + d, hh = gcol >> 6, dd = gcol & 63;
            *(bf16x8*)(vt + ((size_t)((bb * NH + hh) * HD + dd)) * NTOK + tokbase + tc * 8) = v;
        }
    } else {
#pragma unroll
        for (int ni = 0; ni < 4; ++ni) {
            const int col = n0 + wn * 64 + ni * 16 + lm;
#pragma unroll
            for (int mi = 0; mi < 4; ++mi)
#pragma unroll
                for (int r = 0; r < 4; ++r) {
                    const int row = m0 + wm * 64 + mi * 16 + quad * 4 + r;
                    Cq[(size_t)row * N + col] = (bf16)acc[mi][ni][r];
                }
        }
    }
}

// Proj GEMM: 64x128 tile (512 blocks = 2/CU), same reg-prefetch structure.
__global__ __launch_bounds__(256, 3) void gemm_proj(
    const bf16* __restrict__ A, const bf16* __restrict__ B,
    const float* __restrict__ bias, float* __restrict__ C,
    int M, int N, int K)
{
    __shared__ __align__(16) bf16 smem[12288];   // As [0,4096), Bs [4096,12288)

    const int tid  = threadIdx.x;
    const int w    = tid >> 6, lane = tid & 63;
    const int wm   = w & 1,  wn = w >> 1;
    const int m0   = blockIdx.y * 64, n0 = blockIdx.x * 128;
    const int lm   = lane & 15, quad = lane >> 4;

    // A: chunks c = t*256+tid = kc*64+row, row = tid&63, kc = t*4+(tid>>6)
    const bf16* Arow = A + (size_t)(m0 + (tid & 63)) * K + (tid >> 6) * 8;
    // B: as in qkv
    const bf16* Brow = B + (size_t)(n0 + (tid & 127)) * K + (tid >> 7) * 8;

    bf16x8 ar[2], br[4];
#define PROJ_LOADREG(kt) do {                                   \
    for (int t = 0; t < 2; ++t)                                 \
        ar[t] = *(const bf16x8*)(Arow + (kt) + t * 32);         \
    for (int t = 0; t < 4; ++t)                                 \
        br[t] = *(const bf16x8*)(Brow + (kt) + t * 16);         \
    } while (0)
#define PROJ_DSWRITE() do {                                     \
    for (int t = 0; t < 2; ++t)                                 \
        *(bf16x8*)(smem + (t * 256 + tid) * 8) = ar[t];         \
    for (int t = 0; t < 4; ++t)                                 \
        *(bf16x8*)(smem + 4096 + (t * 256 + tid) * 8) = br[t];  \
    } while (0)

    f32x4 acc[2][4];
    f32x4 z4 = {0.f, 0.f, 0.f, 0.f};
#pragma unroll
    for (int i = 0; i < 2; ++i)
#pragma unroll
        for (int j = 0; j < 4; ++j) acc[i][j] = z4;

    const int NI = K / 64;
    PROJ_LOADREG(0);
    PROJ_DSWRITE();
    __syncthreads();
    for (int it = 0; it < NI; ++it) {
        if (it + 1 < NI) PROJ_LOADREG((it + 1) * 64);
#pragma unroll
        for (int s = 0; s < 2; ++s) {
            bf16x8 af[2], bf_[4];
#pragma unroll
            for (int mi = 0; mi < 2; ++mi)
                af[mi] = *(const bf16x8*)(smem
                    + ((s * 4 + quad) * 64 + wm * 32 + mi * 16 + lm) * 8);
#pragma unroll
            for (int ni = 0; ni < 4; ++ni)
                bf_[ni] = *(const bf16x8*)(smem + 4096
                    + ((s * 4 + quad) * 128 + wn * 64 + ni * 16 + lm) * 8);
#pragma unroll
            for (int mi = 0; mi < 2; ++mi)
#pragma unroll
                for (int ni = 0; ni < 4; ++ni)
                    acc[mi][ni] = mfma16(af[mi], bf_[ni], acc[mi][ni]);
        }
        __syncthreads();
        if (it + 1 < NI) PROJ_DSWRITE();
        __syncthreads();
    }
#undef PROJ_LOADREG
#undef PROJ_DSWRITE

#pragma unroll
    for (int ni = 0; ni < 4; ++ni) {
        const int col = n0 + wn * 64 + ni * 16 + lm;
        const float bi = bias[col];
#pragma unroll
        for (int mi = 0; mi < 2; ++mi)
#pragma unroll
            for (int r = 0; r < 4; ++r) {
                const int row = m0 + wm * 32 + mi * 16 + quad * 4 + r;
                C[(size_t)row * N + col] = acc[mi][ni][r] + bi;
            }
    }
}

// ---------------------------------------------------------------------------
// Flash attention, bf16 MFMA, software-pipelined K-loop (round 6, unchanged).
// ---------------------------------------------------------------------------
__global__ __launch_bounds__(256, 2) void attn_mfma(
    const bf16* __restrict__ qkv,   // [B,N,3C] bf16 (Q,K cols only)
    const bf16* __restrict__ Vt,    // [B,H,D,N] bf16
    bf16* __restrict__ att)         // [B,N,C]  bf16
{
    __shared__ __align__(16) bf16 Ks[2][64 * 64];     // chunk = dc*64 + krow
    __shared__ __align__(16) bf16 Vs[2][64 * 64];     // chunk = kc*64 + d
    __shared__ __align__(16) bf16 Ps[2][128 * 72];    // [q][key] pitch 72

    const int n0 = blockIdx.x * 128, h = blockIdx.y, b = blockIdx.z;
    const int tid = threadIdx.x, w = tid >> 6, lane = tid & 63;
    const int lm = lane & 15, quad = lane >> 4;

    const size_t rs = (size_t)(3 * DIMC);
    const bf16* qbase  = qkv + (size_t)b * NTOK * rs + h * HD;
    const bf16* kbase  = qbase + DIMC;
    const bf16* vtbase = Vt + ((size_t)(b * NH + h) * HD) * NTOK;

    // Q A-frags in registers
    bf16x8 aq[2][2];
#pragma unroll
    for (int g = 0; g < 2; ++g)
#pragma unroll
        for (int s2 = 0; s2 < 2; ++s2)
            aq[g][s2] = *(const bf16x8*)(qbase
                + (size_t)(n0 + w * 32 + g * 16 + lm) * rs + s2 * 32 + quad * 8);

    const int l0 = (w * 2 + 0) * 64 + lane, l1 = (w * 2 + 1) * 64 + lane;
    const bf16* kg0 = kbase + (size_t)(l0 & 63) * rs + (l0 >> 6) * 8;
    const bf16* kg1 = kbase + (size_t)(l1 & 63) * rs + (l1 >> 6) * 8;
    const bf16* vg0 = vtbase + (size_t)(l0 & 63) * NTOK + (l0 >> 6) * 8;
    const bf16* vg1 = vtbase + (size_t)(l1 & 63) * NTOK + (l1 >> 6) * 8;

#define STAGE_K(tile, dst) do { \
    load_lds16(kg0 + (size_t)(tile) * 64 * rs, (dst) + (w * 2 + 0) * 512); \
    load_lds16(kg1 + (size_t)(tile) * 64 * rs, (dst) + (w * 2 + 1) * 512); } while (0)
#define STAGE_V(tile, dst) do { \
    load_lds16(vg0 + (size_t)(tile) * 64, (dst) + (w * 2 + 0) * 512); \
    load_lds16(vg1 + (size_t)(tile) * 64, (dst) + (w * 2 + 1) * 512); } while (0)

    f32x4 O[2][4];
    f32x4 z4 = {0.f, 0.f, 0.f, 0.f};
#pragma unroll
    for (int g = 0; g < 2; ++g)
#pragma unroll
        for (int ni = 0; ni < 4; ++ni) O[g][ni] = z4;
    float lsum[2][4] = {{0.f, 0.f, 0.f, 0.f}, {0.f, 0.f, 0.f, 0.f}};

#define COMPUTE_S_PS(Ksb, Psb) do {                                           \
    f32x4 S[2][4];                                                            \
    for (int g = 0; g < 2; ++g)                                               \
        for (int ni = 0; ni < 4; ++ni) S[g][ni] = z4;                         \
    for (int s2 = 0; s2 < 2; ++s2)                                            \
        for (int ni = 0; ni < 4; ++ni) {                                      \
            bf16x8 bk = *(const bf16x8*)((Ksb)                                \
                + ((s2 * 4 + quad) * 64 + ni * 16 + lm) * 8);                 \
            S[0][ni] = mfma16(aq[0][s2], bk, S[0][ni]);                       \
            S[1][ni] = mfma16(aq[1][s2], bk, S[1][ni]);                       \
        }                                                                     \
    for (int g = 0; g < 2; ++g)                                               \
        for (int ni = 0; ni < 4; ++ni)                                        \
            for (int r = 0; r < 4; ++r) {                                     \
                const float p = __builtin_amdgcn_exp2f(S[g][ni][r] * SOFT_K2);\
                (Psb)[(w * 32 + g * 16 + quad * 4 + r) * 72 + ni * 16 + lm]   \
                    = (bf16)p;                                                \
                lsum[g][r] += p;                                              \
            }                                                                 \
} while (0)

#define COMPUTE_PV(Psb, Vsb) do {                                             \
    for (int s2 = 0; s2 < 2; ++s2) {                                          \
        bf16x8 ap0 = *(const bf16x8*)((Psb)                                   \
            + (w * 32 + lm) * 72 + s2 * 32 + quad * 8);                       \
        bf16x8 ap1 = *(const bf16x8*)((Psb)                                   \
            + (w * 32 + 16 + lm) * 72 + s2 * 32 + quad * 8);                  \
        for (int ni = 0; ni < 4; ++ni) {                                      \
            bf16x8 bv = *(const bf16x8*)((Vsb)                                \
                + ((s2 * 4 + quad) * 64 + ni * 16 + lm) * 8);                 \
            O[0][ni] = mfma16(ap0, bv, O[0][ni]);                             \
            O[1][ni] = mfma16(ap1, bv, O[1][ni]);                             \
        }                                                                     \
    }                                                                         \
} while (0)

    const int NT = NTOK / 64;   // 32

    STAGE_K(0, Ks[0]);
    STAGE_V(0, Vs[0]);
    STAGE_K(1, Ks[1]);
    __syncthreads();
    COMPUTE_S_PS(Ks[0], Ps[0]);

    for (int t = 0; t < NT; ++t) {
        __syncthreads();
        if (t + 2 < NT) STAGE_K(t + 2, Ks[t & 1]);
        if (t + 1 < NT) STAGE_V(t + 1, Vs[(t + 1) & 1]);
        if (t + 1 < NT) COMPUTE_S_PS(Ks[(t + 1) & 1], Ps[(t + 1) & 1]);
        COMPUTE_PV(Ps[t & 1], Vs[t & 1]);
    }

#undef STAGE_K
#undef STAGE_V
#undef COMPUTE_S_PS
#undef COMPUTE_PV

#pragma unroll
    for (int g = 0; g < 2; ++g)
#pragma unroll
        for (int r = 0; r < 4; ++r) {
#pragma unroll
            for (int msk = 1; msk < 16; msk <<= 1)
                lsum[g][r] += __shfl_xor(lsum[g][r], msk);
        }

#pragma unroll
    for (int g = 0; g < 2; ++g)
#pragma unroll
        for (int r = 0; r < 4; ++r) {
            const float invl = 1.0f / lsum[g][r];
            const size_t row = (size_t)(b * NTOK + n0 + w * 32 + g * 16 + quad * 4 + r);
#pragma unroll
            for (int ni = 0; ni < 4; ++ni)
                att[row * DIMC + h * HD + ni * 16 + lm] = (bf16)(O[g][ni][r] * invl);
        }
}

// ---------------------------------------------------------------------------
extern "C" void kernel_launch(void* const* d_in, const int* in_sizes, int n_in,
                              void* d_out, int out_size, void* d_ws, size_t ws_size,
                              hipStream_t stream)
{
    const float* x      = (const float*)d_in[0];   // [2,2048,1024]
    const float* W_qkv  = (const float*)d_in[1];   // [3072,1024]
    const float* W_proj = (const float*)d_in[2];   // [1024,1024]
    const float* b_proj = (const float*)d_in[3];   // [1024]
    float* out = (float*)d_out;

    char* ws = (char*)d_ws;
    bf16* xb   = (bf16*)ws;                        //  8 MiB
    bf16* w1b  = (bf16*)(ws + (8u  << 20));        //  6 MiB
    bf16* w2b  = (bf16*)(ws + (14u << 20));        //  2 MiB
    bf16* qkvb = (bf16*)(ws + (16u << 20));        // 24 MiB (V cols unused)
    bf16* vt   = (bf16*)(ws + (40u << 20));        //  8 MiB
    bf16* attb = (bf16*)(ws + (48u << 20));        //  8 MiB (total 56 MiB)

    const int M = BATCH * NTOK;   // 4096

    cast3<<<8192, 256, 0, stream>>>(x, W_qkv, W_proj, xb, w1b, w2b);

    gemm_qkv<<<dim3((3 * DIMC) / 128, M / 128), 256, 0, stream>>>(
        xb, w1b, qkvb, vt, M, 3 * DIMC, DIMC);

    attn_mfma<<<dim3(NTOK / 128, NH, BATCH), 256, 0, stream>>>(qkvb, vt, attb);

    gemm_proj<<<dim3(DIMC / 128, M / 64), 256, 0, stream>>>(
        attb, w2b, b_proj, out, M, DIMC, DIMC);
}